// Round 13
// baseline (710.564 us; speedup 1.0000x reference)
//
#include <hip/hip_runtime.h>

typedef _Float16 f16x8 __attribute__((ext_vector_type(8)));
typedef _Float16 f16x4 __attribute__((ext_vector_type(4)));
typedef float f32x4 __attribute__((ext_vector_type(4)));

// GraphSAGE 3-layer, mean aggregator, eval mode. f16 storage + MFMA GEMM.
// R7: (1) sort passes A/C at EPB=2048 with bijective XCD-chunked work swizzle;
//     (2) aggregate uses v_fma_mix_f32 (bit-identical to cvt+add);
//     (3) layer 2 transform-first: K=128 GEMM -> [d_out fp32 | T f16], then
//     64-dim aggregate-add.
// R10 FIX: gemm_final was acc[4][2]/j<2 (32 cols/wave); geometry needs CF=4
//     (64 cols/wave). Cols 32-63 & 96-127 were never written -> absmax 0.626.

#define BSHIFT 7
#define BSZ 128           // nodes per bucket
#define EPB 2048          // edges per work chunk in passes A/C

// bijective XCD-chunked work mapping (m204): XCD k = b%8 owns contiguous chunks
__device__ __forceinline__ int work_of_block(int b, int nblk) {
  int q = nblk >> 3, r = nblk & 7;
  int x = b & 7, i = b >> 3;
  return (x < r) ? x * (q + 1) + i : r * (q + 1) + (x - r) * q + i;
}

// v_fma_mix_f32: acc += (f32)f16_half(v); bit-identical to cvt+add (x*1.0+c)
__device__ __forceinline__ void mixlo(float& a, unsigned v) {
  asm("v_fma_mix_f32 %0, %1, 1.0, %0 op_sel:[0,0,0] op_sel_hi:[1,0,0]"
      : "+v"(a) : "v"(v));
}
__device__ __forceinline__ void mixhi(float& a, unsigned v) {
  asm("v_fma_mix_f32 %0, %1, 1.0, %0 op_sel:[1,0,0] op_sel_hi:[1,0,0]"
      : "+v"(a) : "v"(v));
}

// ------------------------------------------------------------- sort pass A
__global__ __launch_bounds__(256) void histA(const int* __restrict__ dst,
                                             int* __restrict__ hist_pb,
                                             int n_edges, int nbk, int nblk) {
  __shared__ unsigned lh[1024];
  for (int i = threadIdx.x; i < nbk; i += 256) lh[i] = 0;
  __syncthreads();
  int w = work_of_block(blockIdx.x, nblk);
  int base = w * EPB;
  for (int i = threadIdx.x; i < EPB; i += 256) {
    int e = base + i;
    if (e < n_edges) atomicAdd(&lh[dst[e] >> BSHIFT], 1u);
  }
  __syncthreads();
  for (int i = threadIdx.x; i < nbk; i += 256)
    hist_pb[(size_t)w * nbk + i] = (int)lh[i];
}

// ------------------------------------------------------------- sort pass B
__global__ __launch_bounds__(256) void sumB1(const int* __restrict__ hist_pb,
                                             int* __restrict__ btot, int nblk, int nbk) {
  int b = blockIdx.x * 256 + threadIdx.x;
  if (b >= nbk) return;
  int s = 0;
  for (int k = 0; k < nblk; ++k) s += hist_pb[(size_t)k * nbk + b];
  btot[b] = s;
}

__global__ __launch_bounds__(1024) void scanB2(const int* __restrict__ btot,
                                               int* __restrict__ bbase, int nbk) {
  __shared__ int buf[1024];
  int t = threadIdx.x;
  int v = (t < nbk) ? btot[t] : 0;
  int x = v;
  buf[t] = x;
  __syncthreads();
#pragma unroll
  for (int off = 1; off < 1024; off <<= 1) {
    int tm = (t >= off) ? buf[t - off] : 0;
    __syncthreads();
    x += tm;
    buf[t] = x;
    __syncthreads();
  }
  if (t < nbk) bbase[t] = x - v;          // exclusive
  if (t == nbk - 1) bbase[nbk] = x;       // total edge count
}

__global__ __launch_bounds__(256) void offsB3(int* __restrict__ hist_pb,
                                              const int* __restrict__ bbase,
                                              int nblk, int nbk) {
  int b = blockIdx.x * 256 + threadIdx.x;
  if (b >= nbk) return;
  int run = bbase[b];
  for (int k = 0; k < nblk; ++k) {
    int t = hist_pb[(size_t)k * nbk + b];
    hist_pb[(size_t)k * nbk + b] = run;
    run += t;
  }
}

// ------------------------------------------------------------- sort pass C
__global__ __launch_bounds__(256) void scatC(const int* __restrict__ src,
                                             const int* __restrict__ dst,
                                             const int* __restrict__ hist_pb,
                                             unsigned* __restrict__ pairs,
                                             int n_edges, int nbk, int nblk) {
  __shared__ unsigned lofs[1024];
  int w = work_of_block(blockIdx.x, nblk);
  for (int i = threadIdx.x; i < nbk; i += 256)
    lofs[i] = (unsigned)hist_pb[(size_t)w * nbk + i];
  __syncthreads();
  int base = w * EPB;
  for (int i = threadIdx.x; i < EPB; i += 256) {
    int e = base + i;
    if (e < n_edges) {
      int d = dst[e];
      unsigned pos = atomicAdd(&lofs[d >> BSHIFT], 1u);
      pairs[pos] = ((unsigned)(d & (BSZ - 1)) << 18) | (unsigned)src[e];
    }
  }
}

// ------------------------------------------------------------- sort pass D
__global__ __launch_bounds__(256) void finalD(const unsigned* __restrict__ pairs,
                                              const int* __restrict__ bbase,
                                              int* __restrict__ row_ptr,
                                              int* __restrict__ src_sorted,
                                              int n, int nbk) {
  __shared__ int ldeg[BSZ];
  __shared__ int lscan[BSZ];
  __shared__ int lcur[BSZ];
  int b = blockIdx.x;
  int t = threadIdx.x;
  int node0 = b << BSHIFT;
  int beg = bbase[b], end = bbase[b + 1];
  if (t < BSZ) ldeg[t] = 0;
  __syncthreads();
  for (int i = beg + t; i < end; i += 256) atomicAdd(&ldeg[pairs[i] >> 18], 1);
  __syncthreads();
  int x = (t < BSZ) ? ldeg[t] : 0;
  if (t < BSZ) lscan[t] = x;
  __syncthreads();
#pragma unroll
  for (int off = 1; off < BSZ; off <<= 1) {
    int tm = (t >= off && t < BSZ) ? lscan[t - off] : 0;
    __syncthreads();
    if (t < BSZ) {
      x += tm;
      lscan[t] = x;
    }
    __syncthreads();
  }
  if (t < BSZ) {
    int node = node0 + t;
    lcur[t] = beg + lscan[t] - ldeg[t];  // exclusive start (global)
    if (node < n) {
      row_ptr[node + 1] = beg + lscan[t];
      if (node == 0) row_ptr[0] = 0;
    }
  }
  __syncthreads();
  for (int i = beg + t; i < end; i += 256) {
    unsigned p = pairs[i];
    int pos = atomicAdd(&lcur[p >> 18], 1);
    src_sorted[pos] = (int)(p & 0x3FFFFu);
  }
}

// ------------------------------------------------------- f16 preprocessing
__global__ __launch_bounds__(256) void convert_features(const float* __restrict__ f,
                                                        _Float16* __restrict__ X, int n) {
  int idx = blockIdx.x * 256 + threadIdx.x;
  int total = n * 32;
  if (idx >= total) return;
  int node = idx >> 5;
  int c4 = (idx & 31) * 4;
  float4 v = *(const float4*)(f + (size_t)node * 128 + c4);
  _Float16* o = X + (size_t)node * 256 + c4;
  o[0] = (_Float16)v.x;
  o[1] = (_Float16)v.y;
  o[2] = (_Float16)v.z;
  o[3] = (_Float16)v.w;
}

__global__ __launch_bounds__(256) void build_wt(const float* __restrict__ Ws,
                                                const float* __restrict__ Wn,
                                                _Float16* __restrict__ Wt, int NOUT) {
  int idx = blockIdx.x * 256 + threadIdx.x;
  if (idx >= NOUT * 256) return;
  int nn = idx >> 8;
  int k = idx & 255;
  float v = (k < 128) ? Ws[(size_t)k * NOUT + nn] : Wn[(size_t)(k - 128) * NOUT + nn];
  Wt[(size_t)nn * 256 + k] = (_Float16)v;
}

// Wt2cat[nn][k] (128x128): nn<64 -> Ws2[k][nn] ; else Wn2[k][nn-64]
__global__ __launch_bounds__(256) void build_wt2cat(const float* __restrict__ Ws2,
                                                    const float* __restrict__ Wn2,
                                                    _Float16* __restrict__ Wt) {
  int idx = blockIdx.x * 256 + threadIdx.x;
  if (idx >= 128 * 128) return;
  int nn = idx >> 7;
  int k = idx & 127;
  float v = (nn < 64) ? Ws2[(size_t)k * 64 + nn] : Wn2[(size_t)k * 64 + (nn - 64)];
  Wt[(size_t)nn * 128 + k] = (_Float16)v;
}

// ---------------------------------------------------------- mean aggregation
// Wave per dst node. lane = (edge-slot es=l>>5, feature-quad fh=l&31).
// 8 edges (2KB) in flight; v_fma_mix accumulate (1 VALU op / element).
__global__ __launch_bounds__(256) void aggregate_f16(
    const _Float16* __restrict__ X, const int* __restrict__ row_ptr,
    const int* __restrict__ src_sorted, _Float16* __restrict__ Xout, int n) {
  int gid = blockIdx.x * 256 + threadIdx.x;
  int node = gid >> 6;
  if (node >= n) return;
  int lane = threadIdx.x & 63;
  int fh = lane & 31;   // feature quad -> features [fh*4, fh*4+4)
  int es = lane >> 5;   // edge slot
  int beg = row_ptr[node];
  int end = row_ptr[node + 1];
  float a0 = 0.f, a1 = 0.f, a2 = 0.f, a3 = 0.f;
  int e = beg;
  for (; e + 8 <= end; e += 8) {
    int s0 = src_sorted[e + 0 + es];
    int s1 = src_sorted[e + 2 + es];
    int s2 = src_sorted[e + 4 + es];
    int s3 = src_sorted[e + 6 + es];
    uint2 v0 = *(const uint2*)(X + (size_t)s0 * 256 + fh * 4);
    uint2 v1 = *(const uint2*)(X + (size_t)s1 * 256 + fh * 4);
    uint2 v2 = *(const uint2*)(X + (size_t)s2 * 256 + fh * 4);
    uint2 v3 = *(const uint2*)(X + (size_t)s3 * 256 + fh * 4);
    mixlo(a0, v0.x); mixhi(a1, v0.x); mixlo(a2, v0.y); mixhi(a3, v0.y);
    mixlo(a0, v1.x); mixhi(a1, v1.x); mixlo(a2, v1.y); mixhi(a3, v1.y);
    mixlo(a0, v2.x); mixhi(a1, v2.x); mixlo(a2, v2.y); mixhi(a3, v2.y);
    mixlo(a0, v3.x); mixhi(a1, v3.x); mixlo(a2, v3.y); mixhi(a3, v3.y);
  }
  for (; e < end; e += 2) {
    if (e + es < end) {
      int s = src_sorted[e + es];
      uint2 v = *(const uint2*)(X + (size_t)s * 256 + fh * 4);
      mixlo(a0, v.x); mixhi(a1, v.x); mixlo(a2, v.y); mixhi(a3, v.y);
    }
  }
  a0 += __shfl_xor(a0, 32);
  a1 += __shfl_xor(a1, 32);
  a2 += __shfl_xor(a2, 32);
  a3 += __shfl_xor(a3, 32);
  if (es == 0) {
    float inv = 1.0f / fmaxf((float)(end - beg), 1.0f);
    f16x4 o;
    o[0] = (_Float16)(a0 * inv);
    o[1] = (_Float16)(a1 * inv);
    o[2] = (_Float16)(a2 * inv);
    o[3] = (_Float16)(a3 * inv);
    *(f16x4*)(Xout + (size_t)node * 256 + 128 + fh * 4) = o;
  }
}

// 64-dim aggregate-add: d_out[node] += mean_{src} T[src]  (T f16 [n][64])
// lane = (edge-slot es=l>>4 (4 slots), feature-quad fq=l&15). 16 edges in flight.
__global__ __launch_bounds__(256) void aggregate64_add(
    const _Float16* __restrict__ T, const int* __restrict__ row_ptr,
    const int* __restrict__ src_sorted, float* __restrict__ out, int n) {
  int gid = blockIdx.x * 256 + threadIdx.x;
  int node = gid >> 6;
  if (node >= n) return;
  int lane = threadIdx.x & 63;
  int fq = lane & 15;
  int es = lane >> 4;
  int beg = row_ptr[node];
  int end = row_ptr[node + 1];
  float a0 = 0.f, a1 = 0.f, a2 = 0.f, a3 = 0.f;
  int e = beg;
  for (; e + 16 <= end; e += 16) {
    int s0 = src_sorted[e + 0 + es];
    int s1 = src_sorted[e + 4 + es];
    int s2 = src_sorted[e + 8 + es];
    int s3 = src_sorted[e + 12 + es];
    uint2 v0 = *(const uint2*)(T + (size_t)s0 * 64 + fq * 4);
    uint2 v1 = *(const uint2*)(T + (size_t)s1 * 64 + fq * 4);
    uint2 v2 = *(const uint2*)(T + (size_t)s2 * 64 + fq * 4);
    uint2 v3 = *(const uint2*)(T + (size_t)s3 * 64 + fq * 4);
    mixlo(a0, v0.x); mixhi(a1, v0.x); mixlo(a2, v0.y); mixhi(a3, v0.y);
    mixlo(a0, v1.x); mixhi(a1, v1.x); mixlo(a2, v1.y); mixhi(a3, v1.y);
    mixlo(a0, v2.x); mixhi(a1, v2.x); mixlo(a2, v2.y); mixhi(a3, v2.y);
    mixlo(a0, v3.x); mixhi(a1, v3.x); mixlo(a2, v3.y); mixhi(a3, v3.y);
  }
  for (; e < end; e += 4) {
    if (e + es < end) {
      int s = src_sorted[e + es];
      uint2 v = *(const uint2*)(T + (size_t)s * 64 + fq * 4);
      mixlo(a0, v.x); mixhi(a1, v.x); mixlo(a2, v.y); mixhi(a3, v.y);
    }
  }
  a0 += __shfl_xor(a0, 16); a0 += __shfl_xor(a0, 32);
  a1 += __shfl_xor(a1, 16); a1 += __shfl_xor(a1, 32);
  a2 += __shfl_xor(a2, 16); a2 += __shfl_xor(a2, 32);
  a3 += __shfl_xor(a3, 16); a3 += __shfl_xor(a3, 32);
  if (es == 0) {
    float inv = 1.0f / fmaxf((float)(end - beg), 1.0f);
    float4* po = (float4*)(out + (size_t)node * 64 + fq * 4);
    float4 cur = *po;
    cur.x += a0 * inv;
    cur.y += a1 * inv;
    cur.z += a2 * inv;
    cur.w += a3 * inv;
    *po = cur;
  }
}

// ------------------------------------------------------------------- GEMM
template <int NOUT, bool RELU>
__global__ __launch_bounds__(256) void gemm_mfma(
    const _Float16* __restrict__ X, const _Float16* __restrict__ Wt,
    const float* __restrict__ bias, _Float16* __restrict__ outX, int n) {
  constexpr int CW = NOUT / 2;   // cols per wave
  constexpr int CF = CW / 16;    // col frags per wave
  __shared__ _Float16 Xs[128][72];    // +8 pad: frag stride 144B -> <=2-way
  __shared__ _Float16 Wc[NOUT][72];

  int tid = threadIdx.x;
  int lane = tid & 63;
  int wid = tid >> 6;
  int wr = wid >> 1;
  int wc = wid & 1;
  int node0 = blockIdx.x * 128;

  f32x4 acc[4][CF];
#pragma unroll
  for (int i = 0; i < 4; ++i)
#pragma unroll
    for (int j = 0; j < CF; ++j) acc[i][j] = {0.f, 0.f, 0.f, 0.f};

#pragma unroll
  for (int c = 0; c < 4; ++c) {
    int k0 = c * 64;
#pragma unroll
    for (int i = 0; i < 4; ++i) {
      int idx = i * 256 + tid;
      int r = idx >> 3;
      int o = (idx & 7) * 8;
      f16x8 v;
#pragma unroll
      for (int z = 0; z < 8; ++z) v[z] = (_Float16)0.f;
      int node = node0 + r;
      if (node < n) v = *(const f16x8*)(X + (size_t)node * 256 + k0 + o);
      *(f16x8*)&Xs[r][o] = v;
    }
#pragma unroll
    for (int i = 0; i < NOUT / 32; ++i) {
      int idx = i * 256 + tid;
      int r = idx >> 3;
      int o = (idx & 7) * 8;
      *(f16x8*)&Wc[r][o] = *(const f16x8*)(Wt + (size_t)r * 256 + k0 + o);
    }
    __syncthreads();
#pragma unroll
    for (int ks = 0; ks < 2; ++ks) {
      int kk = ks * 32 + (lane >> 4) * 8;
      f16x8 a[4], b[CF];
#pragma unroll
      for (int i = 0; i < 4; ++i)
        a[i] = *(const f16x8*)&Xs[wr * 64 + i * 16 + (lane & 15)][kk];
#pragma unroll
      for (int j = 0; j < CF; ++j)
        b[j] = *(const f16x8*)&Wc[wc * CW + j * 16 + (lane & 15)][kk];
#pragma unroll
      for (int i = 0; i < 4; ++i)
#pragma unroll
        for (int j = 0; j < CF; ++j)
          acc[i][j] = __builtin_amdgcn_mfma_f32_16x16x32_f16(a[i], b[j], acc[i][j], 0, 0, 0);
    }
    __syncthreads();
  }

#pragma unroll
  for (int j = 0; j < CF; ++j) {
    int col = wc * CW + j * 16 + (lane & 15);
    float bv = bias[col];
#pragma unroll
    for (int i = 0; i < 4; ++i) {
#pragma unroll
      for (int q = 0; q < 4; ++q) {
        int row = wr * 64 + i * 16 + (lane >> 4) * 4 + q;
        int node = node0 + row;
        if (node < n) {
          float v = acc[i][j][q] + bv;
          if (RELU) v = fmaxf(v, 0.f);
          outX[(size_t)node * 256 + col] = (_Float16)v;
        }
      }
    }
  }
}

// Layer-2 GEMM: K=128 (X left half), NOUT=128 = [Ws2 | Wn2].
// 2x2 waves, wave tile 64 rows x 64 cols -> CF=4 col frags (R10 fix).
// cols 0..63 (wc=0) -> d_out fp32 (+b2) ; cols 64..127 (wc=1) -> T f16.
__global__ __launch_bounds__(256) void gemm_final(
    const _Float16* __restrict__ X, const _Float16* __restrict__ Wt,
    const float* __restrict__ b2, float* __restrict__ outF,
    _Float16* __restrict__ T, int n) {
  __shared__ _Float16 Xs[128][72];
  __shared__ _Float16 Wc[128][72];

  int tid = threadIdx.x;
  int lane = tid & 63;
  int wid = tid >> 6;
  int wr = wid >> 1;
  int wc = wid & 1;
  int node0 = blockIdx.x * 128;

  f32x4 acc[4][4];
#pragma unroll
  for (int i = 0; i < 4; ++i)
#pragma unroll
    for (int j = 0; j < 4; ++j) acc[i][j] = {0.f, 0.f, 0.f, 0.f};

#pragma unroll
  for (int c = 0; c < 2; ++c) {
    int k0 = c * 64;
#pragma unroll
    for (int i = 0; i < 4; ++i) {
      int idx = i * 256 + tid;
      int r = idx >> 3;
      int o = (idx & 7) * 8;
      f16x8 v;
#pragma unroll
      for (int z = 0; z < 8; ++z) v[z] = (_Float16)0.f;
      int node = node0 + r;
      if (node < n) v = *(const f16x8*)(X + (size_t)node * 256 + k0 + o);
      *(f16x8*)&Xs[r][o] = v;
    }
#pragma unroll
    for (int i = 0; i < 4; ++i) {
      int idx = i * 256 + tid;
      int r = idx >> 3;
      int o = (idx & 7) * 8;
      *(f16x8*)&Wc[r][o] = *(const f16x8*)(Wt + (size_t)r * 128 + k0 + o);
    }
    __syncthreads();
#pragma unroll
    for (int ks = 0; ks < 2; ++ks) {
      int kk = ks * 32 + (lane >> 4) * 8;
      f16x8 a[4], b[4];
#pragma unroll
      for (int i = 0; i < 4; ++i)
        a[i] = *(const f16x8*)&Xs[wr * 64 + i * 16 + (lane & 15)][kk];
#pragma unroll
      for (int j = 0; j < 4; ++j)
        b[j] = *(const f16x8*)&Wc[wc * 64 + j * 16 + (lane & 15)][kk];
#pragma unroll
      for (int i = 0; i < 4; ++i)
#pragma unroll
        for (int j = 0; j < 4; ++j)
          acc[i][j] = __builtin_amdgcn_mfma_f32_16x16x32_f16(a[i], b[j], acc[i][j], 0, 0, 0);
    }
    __syncthreads();
  }

#pragma unroll
  for (int j = 0; j < 4; ++j) {
    int col = wc * 64 + j * 16 + (lane & 15);
    bool left = col < 64;
    float bv = left ? b2[col] : 0.f;
#pragma unroll
    for (int i = 0; i < 4; ++i) {
#pragma unroll
      for (int q = 0; q < 4; ++q) {
        int row = wr * 64 + i * 16 + (lane >> 4) * 4 + q;
        int node = node0 + row;
        if (node < n) {
          float v = acc[i][j][q] + bv;
          if (left)
            outF[(size_t)node * 64 + col] = v;
          else
            T[(size_t)node * 64 + (col - 64)] = (_Float16)v;
        }
      }
    }
  }
}

// ------------------------------------------------------------------ launch
extern "C" void kernel_launch(void* const* d_in, const int* in_sizes, int n_in,
                              void* d_out, int out_size, void* d_ws, size_t ws_size,
                              hipStream_t stream) {
  const float* features = (const float*)d_in[0];
  const int* src = (const int*)d_in[1];
  const int* dst = (const int*)d_in[2];
  const float* Ws0 = (const float*)d_in[3];
  const float* Wn0 = (const float*)d_in[4];
  const float* b0 = (const float*)d_in[5];
  const float* Ws1 = (const float*)d_in[6];
  const float* Wn1 = (const float*)d_in[7];
  const float* b1 = (const float*)d_in[8];
  const float* Ws2 = (const float*)d_in[9];
  const float* Wn2 = (const float*)d_in[10];
  const float* b2 = (const float*)d_in[11];

  const int n = in_sizes[0] / 128;
  const int n_edges = in_sizes[1];
  const int nbk = (n + BSZ - 1) >> BSHIFT;          // 782 buckets
  const int nblk = (n_edges + EPB - 1) / EPB;       // 782 work chunks

  char* ws = (char*)d_ws;
  size_t off = 0;
  auto alloc = [&](size_t bytes) -> void* {
    void* p = ws + off;
    off += (bytes + 255) & ~(size_t)255;
    return p;
  };
  int* hist_pb = (int*)alloc((size_t)nblk * nbk * 4);
  int* btot = (int*)alloc((size_t)nbk * 4);
  int* bbase = (int*)alloc(((size_t)nbk + 1) * 4);
  unsigned* pairs = (unsigned*)alloc((size_t)n_edges * 4);
  int* row_ptr = (int*)alloc(((size_t)n + 1) * 4);
  int* src_sorted = (int*)alloc((size_t)n_edges * 4);
  _Float16* XA = (_Float16*)alloc((size_t)n * 256 * 2);
  _Float16* XB = (_Float16*)alloc((size_t)n * 256 * 2);
  _Float16* T = (_Float16*)alloc((size_t)n * 64 * 2);
  _Float16* Wt0 = (_Float16*)alloc((size_t)128 * 256 * 2);
  _Float16* Wt1 = (_Float16*)alloc((size_t)128 * 256 * 2);
  _Float16* Wt2 = (_Float16*)alloc((size_t)128 * 128 * 2);

  int nbkb = (nbk + 255) / 256;
  histA<<<nblk, 256, 0, stream>>>(dst, hist_pb, n_edges, nbk, nblk);
  sumB1<<<nbkb, 256, 0, stream>>>(hist_pb, btot, nblk, nbk);
  scanB2<<<1, 1024, 0, stream>>>(btot, bbase, nbk);
  offsB3<<<nbkb, 256, 0, stream>>>(hist_pb, bbase, nblk, nbk);
  scatC<<<nblk, 256, 0, stream>>>(src, dst, hist_pb, pairs, n_edges, nbk, nblk);
  finalD<<<nbk, 256, 0, stream>>>(pairs, bbase, row_ptr, src_sorted, n, nbk);

  convert_features<<<(n * 32 + 255) / 256, 256, 0, stream>>>(features, XA, n);
  build_wt<<<(128 * 256 + 255) / 256, 256, 0, stream>>>(Ws0, Wn0, Wt0, 128);
  build_wt<<<(128 * 256 + 255) / 256, 256, 0, stream>>>(Ws1, Wn1, Wt1, 128);
  build_wt2cat<<<(128 * 128 + 255) / 256, 256, 0, stream>>>(Ws2, Wn2, Wt2);

  int agg_blocks = (int)(((size_t)n * 64 + 255) / 256);
  int gemm_blocks = (n + 127) / 128;

  // layer 0
  aggregate_f16<<<agg_blocks, 256, 0, stream>>>(XA, row_ptr, src_sorted, XA, n);
  gemm_mfma<128, true><<<gemm_blocks, 256, 0, stream>>>(XA, Wt0, b0, XB, n);
  // layer 1
  aggregate_f16<<<agg_blocks, 256, 0, stream>>>(XB, row_ptr, src_sorted, XB, n);
  gemm_mfma<128, true><<<gemm_blocks, 256, 0, stream>>>(XB, Wt1, b1, XA, n);
  // layer 2: transform-first, then 64-dim aggregate-add
  gemm_final<<<gemm_blocks, 256, 0, stream>>>(XA, Wt2, b2, (float*)d_out, T, n);
  aggregate64_add<<<agg_blocks, 256, 0, stream>>>(T, row_ptr, src_sorted, (float*)d_out, n);
}